// Round 2
// baseline (5475.207 us; speedup 1.0000x reference)
//
#include <hip/hip_runtime.h>

// Problem constants
// B=8, HW=576, C=4608, C8=CC8=576
// combined: 8*576*4608 = 21,233,664 floats, attn_outs: 3x that.
#define ATTN_OFF 21233664L

// ---------------------------------------------------------------------------
// Generic tiled fp32 GEMM:  C[M][N] = A[M][K] * op(B) + bias
//   TRANSB=1: B is [N][K] row-major (weights, NT)
//   TRANSB=0: B is [K][N] row-major (batched right operand, NN)
// 256 threads. Each thread computes TM x TN via split fragments:
//   rows {ty*4 .. +3} (+ BM/2 offset if TM==8), cols {tx*4 ..} (+ BN/2 if TN==8)
// Batch (blockIdx.z) offsets in ELEMENTS; bMod!=0 applies (z % bMod) to B.
// LDS leading dims padded +4 floats: keeps float4 (16B) alignment
// (132*4B = 33*16B) while breaking the 4-way store-scatter bank conflict
// (stride 128 -> all banks equal; stride 132 -> 2-way, which is free).
// ---------------------------------------------------------------------------
template<int BM, int BN, int BK, int TM, int TN, bool TRANSB>
__launch_bounds__(256)
__global__ void gemm_kernel(const float* __restrict__ A, const float* __restrict__ Bm,
                            const float* __restrict__ bias, float* __restrict__ Cm,
                            int M, int N, int K,
                            long bsA, long bsB, long bsBias, long bsC, int bMod)
{
    __shared__ float As[BK][BM + 4];
    __shared__ float Bs[BK][BN + 4];
    const int tid = threadIdx.x;
    const int tx = tid & 15, ty = tid >> 4;
    const int z = blockIdx.z;
    const int m0 = blockIdx.y * BM;
    const int n0 = blockIdx.x * BN;

    A  += (long)z * bsA;
    Bm += (long)(bMod ? (z % bMod) : z) * bsB;
    Cm += (long)z * bsC;
    const float* biasp = bias ? bias + (long)z * bsBias : nullptr;

    float acc[TM][TN];
#pragma unroll
    for (int i = 0; i < TM; i++)
#pragma unroll
        for (int j = 0; j < TN; j++) acc[i][j] = 0.f;

    constexpr int AF4 = BM * BK / (4 * 256);
    constexpr int BF4 = BN * BK / (4 * 256);

    for (int k0 = 0; k0 < K; k0 += BK) {
        // A tile [BM][BK] -> As[k][m] (transpose scatter)
#pragma unroll
        for (int r = 0; r < AF4; r++) {
            int f = r * 256 + tid;
            int row = f / (BK / 4);
            int kc = (f % (BK / 4)) * 4;
            float4 v4 = *(const float4*)&A[(long)(m0 + row) * K + k0 + kc];
            As[kc + 0][row] = v4.x; As[kc + 1][row] = v4.y;
            As[kc + 2][row] = v4.z; As[kc + 3][row] = v4.w;
        }
        if (TRANSB) {
#pragma unroll
            for (int r = 0; r < BF4; r++) {
                int f = r * 256 + tid;
                int row = f / (BK / 4);
                int kc = (f % (BK / 4)) * 4;
                float4 v4 = *(const float4*)&Bm[(long)(n0 + row) * K + k0 + kc];
                Bs[kc + 0][row] = v4.x; Bs[kc + 1][row] = v4.y;
                Bs[kc + 2][row] = v4.z; Bs[kc + 3][row] = v4.w;
            }
        } else {
#pragma unroll
            for (int r = 0; r < BF4; r++) {
                int f = r * 256 + tid;
                int row = f / (BN / 4);
                int nc = (f % (BN / 4)) * 4;
                *(float4*)&Bs[row][nc] = *(const float4*)&Bm[(long)(k0 + row) * N + n0 + nc];
            }
        }
        __syncthreads();
#pragma unroll
        for (int kk = 0; kk < BK; kk++) {
            float a[TM], b[TN];
            *(float4*)&a[0] = *(const float4*)&As[kk][ty * 4];
            if constexpr (TM == 8) *(float4*)&a[4] = *(const float4*)&As[kk][BM / 2 + ty * 4];
            *(float4*)&b[0] = *(const float4*)&Bs[kk][tx * 4];
            if constexpr (TN == 8) *(float4*)&b[4] = *(const float4*)&Bs[kk][BN / 2 + tx * 4];
#pragma unroll
            for (int i = 0; i < TM; i++)
#pragma unroll
                for (int j = 0; j < TN; j++)
                    acc[i][j] += a[i] * b[j];
        }
        __syncthreads();
    }

    // epilogue: +bias, coalesced float4 stores
#pragma unroll
    for (int ih = 0; ih < TM / 4; ih++) {
#pragma unroll
        for (int i = 0; i < 4; i++) {
            int row = m0 + ih * (BM / 2) + ty * 4 + i;
#pragma unroll
            for (int jh = 0; jh < TN / 4; jh++) {
                int col = n0 + jh * (BN / 2) + tx * 4;
                float4 r;
                r.x = acc[ih * 4 + i][jh * 4 + 0];
                r.y = acc[ih * 4 + i][jh * 4 + 1];
                r.z = acc[ih * 4 + i][jh * 4 + 2];
                r.w = acc[ih * 4 + i][jh * 4 + 3];
                if (biasp) {
                    float4 bv = *(const float4*)&biasp[col];
                    r.x += bv.x; r.y += bv.y; r.z += bv.z; r.w += bv.w;
                }
                *(float4*)&Cm[(long)row * N + col] = r;
            }
        }
    }
}

// ---------------------------------------------------------------------------
// Row softmax over 576 cols, in place. One wave per row.
// ---------------------------------------------------------------------------
__launch_bounds__(64)
__global__ void softmax_kernel(float* __restrict__ att)
{
    long row = blockIdx.x;
    float* p = att + row * 576L;
    int lane = threadIdx.x;
    float vals[9];
    float m = -1e30f;
#pragma unroll
    for (int j = 0; j < 9; j++) { vals[j] = p[lane + j * 64]; m = fmaxf(m, vals[j]); }
    for (int off = 32; off; off >>= 1) m = fmaxf(m, __shfl_xor(m, off));
    float s = 0.f;
#pragma unroll
    for (int j = 0; j < 9; j++) { vals[j] = __expf(vals[j] - m); s += vals[j]; }
    for (int off = 32; off; off >>= 1) s += __shfl_xor(s, off);
    float inv = 1.f / s;
#pragma unroll
    for (int j = 0; j < 9; j++) p[lane + j * 64] = vals[j] * inv;
}

// ---------------------------------------------------------------------------
// Fused PV: for each b, (n,d) tile: out_i = attn_i[b] @ v[b]  (i=0..2),
//   combined = gamma*(o0+o1+o2) + x  (coalesced along d)
//   attn_outs[i][b][d][n] written transposed via LDS.
// Tile 64(n) x 64(d), BK=32. LDS: As[3][32][64] + Bs[32][64] = 32 KB.
// ---------------------------------------------------------------------------
__launch_bounds__(256)
__global__ void pv_combine_kernel(const float* __restrict__ att, const float* __restrict__ v,
                                  const float* __restrict__ x, const float* __restrict__ gamma,
                                  float* __restrict__ out)
{
    constexpr int BK = 32;
    __shared__ float smem[3 * BK * 64 + BK * 64]; // As: [i][k][n] at i*2048; Bs at 6144
    float* Bsp = smem + 6144;

    const int tid = threadIdx.x;
    const int tx = tid & 15, ty = tid >> 4;
    const int d0 = blockIdx.x * 64;
    const int n0 = blockIdx.y * 64;
    const int b = blockIdx.z;

    float acc[3][4][4] = {};

    for (int t0 = 0; t0 < 576; t0 += BK) {
#pragma unroll
        for (int i = 0; i < 3; i++) {
#pragma unroll
            for (int r = 0; r < 2; r++) {
                int f = r * 256 + tid;
                int row = f / 8;            // BK/4 = 8 float4 per row
                int kc = (f % 8) * 4;
                float4 av = *(const float4*)&att[((long)(i * 8 + b) * 576 + n0 + row) * 576 + t0 + kc];
                smem[i * 2048 + (kc + 0) * 64 + row] = av.x;
                smem[i * 2048 + (kc + 1) * 64 + row] = av.y;
                smem[i * 2048 + (kc + 2) * 64 + row] = av.z;
                smem[i * 2048 + (kc + 3) * 64 + row] = av.w;
            }
        }
#pragma unroll
        for (int r = 0; r < 2; r++) {
            int f = r * 256 + tid;
            int row = f / 16;               // 64/4 = 16 float4 per row
            int nc = (f % 16) * 4;
            *(float4*)&Bsp[row * 64 + nc] =
                *(const float4*)&v[((long)b * 576 + t0 + row) * 4608 + d0 + nc];
        }
        __syncthreads();
#pragma unroll
        for (int kk = 0; kk < BK; kk++) {
            float bf[4];
            *(float4*)&bf[0] = *(const float4*)&Bsp[kk * 64 + tx * 4];
#pragma unroll
            for (int i = 0; i < 3; i++) {
                float af[4];
                *(float4*)&af[0] = *(const float4*)&smem[i * 2048 + kk * 64 + ty * 4];
#pragma unroll
                for (int a2 = 0; a2 < 4; a2++)
#pragma unroll
                    for (int b2 = 0; b2 < 4; b2++)
                        acc[i][a2][b2] += af[a2] * bf[b2];
            }
        }
        __syncthreads();
    }

    const float g = gamma[0];
    // combined = g*(o0+o1+o2) + x, coalesced along d
#pragma unroll
    for (int a2 = 0; a2 < 4; a2++) {
        int n = n0 + ty * 4 + a2;
        long base = ((long)b * 576 + n) * 4608 + d0 + tx * 4;
        float4 xv = *(const float4*)&x[base];
        float4 r;
        r.x = g * (acc[0][a2][0] + acc[1][a2][0] + acc[2][a2][0]) + xv.x;
        r.y = g * (acc[0][a2][1] + acc[1][a2][1] + acc[2][a2][1]) + xv.y;
        r.z = g * (acc[0][a2][2] + acc[1][a2][2] + acc[2][a2][2]) + xv.z;
        r.w = g * (acc[0][a2][3] + acc[1][a2][3] + acc[2][a2][3]) + xv.w;
        *(float4*)&out[base] = r;
    }

    // transposed attn_outs via LDS (Tr[d][n], stride 68 keeps float4 alignment)
    for (int i = 0; i < 3; i++) {
        __syncthreads();
#pragma unroll
        for (int a2 = 0; a2 < 4; a2++)
#pragma unroll
            for (int b2 = 0; b2 < 4; b2++)
                smem[(tx * 4 + b2) * 68 + ty * 4 + a2] = acc[i][a2][b2];
        __syncthreads();
#pragma unroll
        for (int rep = 0; rep < 4; rep++) {
            int f = rep * 256 + tid;
            int drow = f / 16;
            int nc = (f % 16) * 4;
            float4 r = *(const float4*)&smem[drow * 68 + nc];
            *(float4*)&out[ATTN_OFF + ((long)(i * 8 + b) * 4608 + d0 + drow) * 576 + n0 + nc] = r;
        }
    }
}

// ---------------------------------------------------------------------------
extern "C" void kernel_launch(void* const* d_in, const int* in_sizes, int n_in,
                              void* d_out, int out_size, void* d_ws, size_t ws_size,
                              hipStream_t stream)
{
    const float* x     = (const float*)d_in[0];
    const float* Wq    = (const float*)d_in[1];
    const float* bq    = (const float*)d_in[2];
    const float* Wk    = (const float*)d_in[3];
    const float* bk    = (const float*)d_in[4];
    const float* Wv    = (const float*)d_in[5];
    const float* bv    = (const float*)d_in[6];
    const float* Wc    = (const float*)d_in[7];
    const float* bc    = (const float*)d_in[8];
    const float* gamma = (const float*)d_in[9];
    float* out = (float*)d_out;

    // workspace layout (floats): q | k | v | cq(3) | attn(3)  = 165.9 MB
    float* q   = (float*)d_ws;
    float* k   = q  + 2654208;   // 8*576*576
    float* v   = k  + 2654208;
    float* cq  = v  + 21233664;  // 8*576*4608
    float* att = cq + 7962624;   // 3*8*576*576

    dim3 blk(256);

    // q = x @ Wq^T + bq ; k likewise. M=4608(tokens), N=576, K=4608
    gemm_kernel<128, 64, 16, 8, 4, true><<<dim3(9, 36, 1), blk, 0, stream>>>(
        x, Wq, bq, q, 4608, 576, 4608, 0, 0, 0, 0, 0);
    gemm_kernel<128, 64, 16, 8, 4, true><<<dim3(9, 36, 1), blk, 0, stream>>>(
        x, Wk, bk, k, 4608, 576, 4608, 0, 0, 0, 0, 0);

    // v = x @ Wv^T + bv. M=4608, N=4608, K=4608 (dominant GEMM)
    gemm_kernel<128, 128, 16, 8, 8, true><<<dim3(36, 36, 1), blk, 0, stream>>>(
        x, Wv, bv, v, 4608, 4608, 4608, 0, 0, 0, 0, 0);

    // cq_i = q @ Wc[i]^T + bc[i], batched over i=0..2. M=4608, N=576, K=576
    gemm_kernel<128, 64, 16, 8, 4, true><<<dim3(9, 36, 3), blk, 0, stream>>>(
        q, Wc, bc, cq, 4608, 576, 576, 0, 331776, 576, 2654208, 0);

    // energy[i,b] = cq_i[b] @ k[b], batched over z=i*8+b (24). NN GEMM 576^3
    gemm_kernel<64, 64, 16, 4, 4, false><<<dim3(9, 9, 24), blk, 0, stream>>>(
        cq, k, nullptr, att, 576, 576, 576, 331776, 331776, 0, 331776, 8);

    // softmax rows (3*8*576 rows of 576)
    softmax_kernel<<<dim3(13824), dim3(64), 0, stream>>>(att);

    // fused PV + combine + transposed attn_outs
    pv_combine_kernel<<<dim3(72, 9, 8), blk, 0, stream>>>(att, v, x, gamma, out);
}